// Round 4
// baseline (1306.104 us; speedup 1.0000x reference)
//
#include <hip/hip_runtime.h>

#define HW 96
#define NPIX 9216      // 96*96
#define NCH 128
#define NB 16

// ---------------- channel mix: mixed[b,c,p] = sum_i lin[c,i] * x[b,i,p] ----------------
// SGEMV-broadcast style: one thread per pixel, all 128 output channels in VGPRs
// (acc[128]). x is read exactly once, fully coalesced, k-octet software prefetch.
// lin[c][k0..k0+7] is wave-uniform -> s_load_dwordx8 from K$-resident 64KB lin.
// NO LDS, NO barriers — R2/R3 counters showed the staged-LDS shape is
// barrier/latency-bound (VALUBusy 42-52%) at this grid size.
template<int K>
__global__ __launch_bounds__(64) void mix_kernel(const float* __restrict__ x,
                                                 const float* __restrict__ lin,
                                                 float* __restrict__ mixed) {
    const int b = blockIdx.y;
    const int p = blockIdx.x * 64 + threadIdx.x;
    const float* xb = x + (size_t)b * K * NPIX + p;

    float acc[NCH];
    #pragma unroll
    for (int c = 0; c < NCH; ++c) acc[c] = 0.f;

    float xv[8];
    #pragma unroll
    for (int j = 0; j < 8; ++j) xv[j] = xb[j * NPIX];

    for (int k0 = 0; k0 < K; k0 += 8) {
        float xn[8];
        if (k0 + 8 < K) {                       // prefetch next octet
            #pragma unroll
            for (int j = 0; j < 8; ++j) xn[j] = xb[(size_t)(k0 + 8 + j) * NPIX];
        }
        const float* lrow = lin + k0;           // lin[c*K + k0 + j], wave-uniform
        #pragma unroll
        for (int c = 0; c < NCH; ++c) {
            #pragma unroll
            for (int j = 0; j < 8; ++j)
                acc[c] = fmaf(lrow[c * K + j], xv[j], acc[c]);
        }
        if (k0 + 8 < K) {
            #pragma unroll
            for (int j = 0; j < 8; ++j) xv[j] = xn[j];
        }
    }
    float* ob = mixed + (size_t)b * NCH * NPIX + p;
    #pragma unroll
    for (int c = 0; c < NCH; ++c) ob[(size_t)c * NPIX] = acc[c];
}

// ---------------- bilinear affine sample ----------------
// ix = t0*w + t1*h + 48*t2 - 47.5*(t0+t1) + 47.5   (identity theta -> ix = w)
struct Taps { int i00, i01, i10, i11; float w00, w01, w10, w11; };

__device__ inline Taps make_taps(const float* __restrict__ th, int h, int w) {
    const float t0 = th[0], t1 = th[1], t2 = th[2];
    const float t3 = th[3], t4 = th[4], t5 = th[5];
    const float ix = t0 * w + t1 * h + (48.f * t2 - 47.5f * (t0 + t1) + 47.5f);
    const float iy = t3 * w + t4 * h + (48.f * t5 - 47.5f * (t3 + t4) + 47.5f);
    const float x0f = floorf(ix), y0f = floorf(iy);
    const float fx = ix - x0f, fy = iy - y0f;
    const int x0 = (int)x0f, y0 = (int)y0f;
    const int x1 = x0 + 1, y1 = y0 + 1;
    const float vx0 = (x0 >= 0 && x0 < HW) ? 1.f : 0.f;
    const float vx1 = (x1 >= 0 && x1 < HW) ? 1.f : 0.f;
    const float vy0 = (y0 >= 0 && y0 < HW) ? 1.f : 0.f;
    const float vy1 = (y1 >= 0 && y1 < HW) ? 1.f : 0.f;
    const int x0c = min(max(x0, 0), HW - 1), x1c = min(max(x1, 0), HW - 1);
    const int y0c = min(max(y0, 0), HW - 1), y1c = min(max(y1, 0), HW - 1);
    Taps tp;
    tp.w00 = (1.f - fy) * (1.f - fx) * vy0 * vx0;
    tp.w01 = (1.f - fy) * fx * vy0 * vx1;
    tp.w10 = fy * (1.f - fx) * vy1 * vx0;
    tp.w11 = fy * fx * vy1 * vx1;
    tp.i00 = y0c * HW + x0c;  tp.i01 = y0c * HW + x1c;
    tp.i10 = y1c * HW + x0c;  tp.i11 = y1c * HW + x1c;
    return tp;
}

// LDS-staged sample: block = (channel c, batch b); whole 36KB plane staged,
// gathers from LDS, coalesced global IO. 384 thr (6 waves) x 4 blocks/CU = 24
// waves/CU for staging-latency hiding. POOL fuses the mean-pool of the final
// feature map (block covers exactly one (b,c) plane -> one pooled value, no atomics).
template<bool RES, bool POOL>
__global__ __launch_bounds__(384) void sample_kernel(const float* __restrict__ mixed,
                                                     const float* __restrict__ geo,
                                                     const float* __restrict__ box,
                                                     float* __restrict__ out,
                                                     float* __restrict__ pooled) {
    __shared__ float m[NPIX];
    const int c = blockIdx.x;
    const int b = blockIdx.y;
    const int t = threadIdx.x;
    const float* src = mixed + ((size_t)b * NCH + c) * NPIX;
    #pragma unroll
    for (int i = 0; i < 6; ++i)
        *(float4*)&m[(i * 384 + t) * 4] = *(const float4*)&src[(i * 384 + t) * 4];
    const float* gth = geo + c * 6;
    const float* bth = box + c * 6;
    float* o = out + ((size_t)b * NCH + c) * NPIX;
    __syncthreads();
    float psum = 0.f;
    #pragma unroll 4
    for (int r = 0; r < NPIX / 384; ++r) {
        const int p = r * 384 + t;
        const int h = p / 96;
        const int w = p - h * 96;
        const Taps g  = make_taps(gth, h, w);
        const Taps bx = make_taps(bth, h, w);
        const float bw = bx.w00 + bx.w01 + bx.w10 + bx.w11;   // box-sample of ones
        float v = g.w00 * m[g.i00] + g.w01 * m[g.i01]
                + g.w10 * m[g.i10] + g.w11 * m[g.i11];
        v *= bw;
        if (RES) v += o[p];
        o[p] = v;
        if (POOL) psum += v;
    }
    if (POOL) {
        #pragma unroll
        for (int off = 32; off > 0; off >>= 1) psum += __shfl_down(psum, off, 64);
        __shared__ float red[6];
        if ((t & 63) == 0) red[t >> 6] = psum;
        __syncthreads();
        if (t == 0) {
            float s = 0.f;
            #pragma unroll
            for (int i = 0; i < 6; ++i) s += red[i];
            pooled[b * NCH + c] = s * (1.f / (float)NPIX);
        }
    }
}

// ---------------- mean pool over H,W (fallback when ws has no room for pooled) ----------------
__global__ __launch_bounds__(256) void pool_kernel(const float* __restrict__ feat,
                                                   float* __restrict__ pooled) {
    const int bc = blockIdx.x;           // b*128 + c
    const float4* f = (const float4*)(feat + (size_t)bc * NPIX);
    float s = 0.f;
    for (int i = threadIdx.x; i < NPIX / 4; i += 256) {
        const float4 v = f[i];
        s += (v.x + v.y) + (v.z + v.w);
    }
    #pragma unroll
    for (int off = 32; off > 0; off >>= 1) s += __shfl_down(s, off, 64);
    __shared__ float red[4];
    if ((threadIdx.x & 63) == 0) red[threadIdx.x >> 6] = s;
    __syncthreads();
    if (threadIdx.x == 0)
        pooled[bc] = (red[0] + red[1] + red[2] + red[3]) * (1.f / (float)NPIX);
}

// ---------------- dense: logits[b,n] = pooled[b,:] . W[n,:] + bias[n] ----------------
__global__ __launch_bounds__(256) void dense_kernel(const float* __restrict__ pooled,
                                                    const float* __restrict__ Wt,
                                                    const float* __restrict__ bias,
                                                    float* __restrict__ out) {
    const int idx = blockIdx.x * 256 + threadIdx.x;
    if (idx >= NB * 1000) return;
    const int b = idx / 1000, n = idx - b * 1000;
    float acc = bias[n];
    const float* p = pooled + b * NCH;
    const float* wr = Wt + n * NCH;
    #pragma unroll 4
    for (int c = 0; c < NCH; ++c) acc = fmaf(p[c], wr[c], acc);
    out[idx] = acc;
}

extern "C" void kernel_launch(void* const* d_in, const int* in_sizes, int n_in,
                              void* d_out, int out_size, void* d_ws, size_t ws_size,
                              hipStream_t stream) {
    const float* x       = (const float*)d_in[0];   // [16,64,96,96]
    const float* in_geo  = (const float*)d_in[1];   // [128,2,3]
    const float* in_box  = (const float*)d_in[2];   // [128,2,3]
    const float* in_lin  = (const float*)d_in[3];   // [128,64]
    const float* lay_geo = (const float*)d_in[4];   // [4,128,2,3]
    const float* lay_box = (const float*)d_in[5];   // [4,128,2,3]
    const float* lay_lin = (const float*)d_in[6];   // [4,128,128]
    const float* dense_w = (const float*)d_in[7];   // [1000,128]
    const float* dense_b = (const float*)d_in[8];   // [1000]

    float* out  = (float*)d_out;
    float* feat = out + NB * 1000;                  // [16,128,96,96] lives in d_out
    float* mixed = (float*)d_ws;                    // 75.5 MB scratch

    const size_t mixedFloats = (size_t)NB * NCH * NPIX;
    const bool fusedPool = ws_size >= (mixedFloats + NB * NCH) * sizeof(float);
    // fused path: pooled lives after mixed (sample reads mixed while writing pooled)
    // fallback: pooled overlays mixed base (only written after mixed is dead)
    float* pooled = fusedPool ? (float*)d_ws + mixedFloats : (float*)d_ws;

    const dim3 mixGrid(NPIX / 64, NB);
    const dim3 smpGrid(NCH, NB);

    mix_kernel<64><<<mixGrid, 64, 0, stream>>>(x, in_lin, mixed);
    sample_kernel<false, false><<<smpGrid, 384, 0, stream>>>(mixed, in_geo, in_box, feat, pooled);
    for (int i = 0; i < 3; ++i) {
        mix_kernel<128><<<mixGrid, 64, 0, stream>>>(feat, lay_lin + i * NCH * NCH, mixed);
        sample_kernel<true, false><<<smpGrid, 384, 0, stream>>>(mixed, lay_geo + i * NCH * 6,
                                                                lay_box + i * NCH * 6, feat, pooled);
    }
    mix_kernel<128><<<mixGrid, 64, 0, stream>>>(feat, lay_lin + 3 * NCH * NCH, mixed);
    if (fusedPool) {
        sample_kernel<true, true><<<smpGrid, 384, 0, stream>>>(mixed, lay_geo + 3 * NCH * 6,
                                                               lay_box + 3 * NCH * 6, feat, pooled);
    } else {
        sample_kernel<true, false><<<smpGrid, 384, 0, stream>>>(mixed, lay_geo + 3 * NCH * 6,
                                                                lay_box + 3 * NCH * 6, feat, pooled);
        pool_kernel<<<NB * NCH, 256, 0, stream>>>(feat, pooled);
    }
    dense_kernel<<<(NB * 1000 + 255) / 256, 256, 0, stream>>>(pooled, dense_w, dense_b, out);
}

// Round 5
// 625.343 us; speedup vs baseline: 2.0886x; 2.0886x over previous
//
#include <hip/hip_runtime.h>

#define HW 96
#define NPIX 9216      // 96*96
#define NCH 128
#define NB 16
#define HP 98          // haloed plane dim (coords -1..96)

// ---------------- channel mix: mixed[b,c,p] = sum_i lin[c,i] * x[b,i,p] ----------------
// No-LDS GEMM: block = 512 thr (8 waves), tile = 256 px x 128 ch.
// Thread = 4 px (x loaded straight from global, coalesced float4, used only by
// this thread). Wave = 16 ch: lin indices wave-uniform (readfirstlane) ->
// s_load_dwordx4 into SGPRs, consumed as the one SGPR operand of v_fma.
// acc 64 + xv 16 + addr ~= 105 VGPR -> 2 blocks/CU, zero barriers, zero LDS.
// (R4: acc[128]/thread spilled, VGPR_Count=84, 219us. R2/R3: LDS-staged shape
// barrier-bound at 42-52% VALU.)
template<int K>
__global__ __launch_bounds__(512, 4) void mix_kernel(const float* __restrict__ x,
                                                     const float* __restrict__ lin,
                                                     float* __restrict__ mixed) {
    const int b    = blockIdx.y;
    const int lane = threadIdx.x & 63;
    const int p    = blockIdx.x * 256 + lane * 4;
    const int c0   = __builtin_amdgcn_readfirstlane((threadIdx.x >> 6) * 16);
    const float* xb = x + (size_t)b * K * NPIX + p;
    const float* lr = lin + c0 * K;

    float4 acc[16];
    #pragma unroll
    for (int c = 0; c < 16; ++c) acc[c] = float4{0.f, 0.f, 0.f, 0.f};

    for (int k0 = 0; k0 < K; k0 += 4) {
        const float4 x0 = *(const float4*)&xb[(size_t)(k0 + 0) * NPIX];
        const float4 x1 = *(const float4*)&xb[(size_t)(k0 + 1) * NPIX];
        const float4 x2 = *(const float4*)&xb[(size_t)(k0 + 2) * NPIX];
        const float4 x3 = *(const float4*)&xb[(size_t)(k0 + 3) * NPIX];
        #pragma unroll
        for (int c = 0; c < 16; ++c) {
            const float* lc = lr + c * K + k0;     // wave-uniform -> s_load_dwordx4
            const float l0 = lc[0], l1 = lc[1], l2 = lc[2], l3 = lc[3];
            acc[c].x = fmaf(l0, x0.x, acc[c].x);
            acc[c].y = fmaf(l0, x0.y, acc[c].y);
            acc[c].z = fmaf(l0, x0.z, acc[c].z);
            acc[c].w = fmaf(l0, x0.w, acc[c].w);
            acc[c].x = fmaf(l1, x1.x, acc[c].x);
            acc[c].y = fmaf(l1, x1.y, acc[c].y);
            acc[c].z = fmaf(l1, x1.z, acc[c].z);
            acc[c].w = fmaf(l1, x1.w, acc[c].w);
            acc[c].x = fmaf(l2, x2.x, acc[c].x);
            acc[c].y = fmaf(l2, x2.y, acc[c].y);
            acc[c].z = fmaf(l2, x2.z, acc[c].z);
            acc[c].w = fmaf(l2, x2.w, acc[c].w);
            acc[c].x = fmaf(l3, x3.x, acc[c].x);
            acc[c].y = fmaf(l3, x3.y, acc[c].y);
            acc[c].z = fmaf(l3, x3.z, acc[c].z);
            acc[c].w = fmaf(l3, x3.w, acc[c].w);
        }
    }
    float* ob = mixed + (size_t)b * NCH * NPIX + p;
    #pragma unroll
    for (int c = 0; c < 16; ++c)
        *(float4*)&ob[(size_t)(c0 + c) * NPIX] = acc[c];
}

__device__ inline float clamp01(float z) { return fminf(fmaxf(z, 0.f), 1.f); }

// ---------------- bilinear affine sample (zero-halo LDS plane) ----------------
// Plane staged into LDS with a 1px zero border (coords -1..96). ix clamped to
// [-1,96] via med3: every out-of-range tap then reads a zero cell with the
// correct weight (verified case-by-case), eliminating all validity masks.
// Box-sample-of-ones factorizes exactly: bw = Xs*Ys,
//   Xs = min(clamp01(ix+1), clamp01(96-ix)) — no floor, no gather.
// 2-lerp form = 6 FMA. ~40 VALU/px vs ~100 before -> memory-bound.
template<bool RES, bool POOL>
__global__ __launch_bounds__(384) void sample_kernel(const float* __restrict__ mixed,
                                                     const float* __restrict__ geo,
                                                     const float* __restrict__ box,
                                                     float* __restrict__ out,
                                                     float* __restrict__ pooled) {
    __shared__ float m[HP * HP];           // 38.4 KB -> 4 blocks/CU, 24 waves/CU
    const int c = blockIdx.x;
    const int b = blockIdx.y;
    const int t = threadIdx.x;
    // zero whole plane (cheap), then fill interior
    #pragma unroll
    for (int i = t; i < (HP * HP) / 4 + 1; i += 384)
        if (i * 4 < HP * HP) *(float4*)&m[i * 4] = float4{0.f, 0.f, 0.f, 0.f};
    __syncthreads();
    const float* src = mixed + ((size_t)b * NCH + c) * NPIX;
    #pragma unroll
    for (int r = 0; r < NPIX / 384; ++r) {
        const int idx = r * 384 + t;
        const int h = idx / 96, w = idx - (idx / 96) * 96;
        m[(h + 1) * HP + (w + 1)] = src[idx];
    }
    const float* gth = geo + c * 6;
    const float* bth = box + c * 6;
    const float g0 = gth[0], g1 = gth[1], g3 = gth[3], g4 = gth[4];
    const float gcx = 48.f * gth[2] - 47.5f * (g0 + g1) + 47.5f;
    const float gcy = 48.f * gth[5] - 47.5f * (g3 + g4) + 47.5f;
    const float b0 = bth[0], b1 = bth[1], b3 = bth[3], b4 = bth[4];
    const float bcx = 48.f * bth[2] - 47.5f * (b0 + b1) + 47.5f;
    const float bcy = 48.f * bth[5] - 47.5f * (b3 + b4) + 47.5f;
    float* o = out + ((size_t)b * NCH + c) * NPIX;
    __syncthreads();
    float psum = 0.f;
    #pragma unroll 4
    for (int r = 0; r < NPIX / 384; ++r) {
        const int p = r * 384 + t;
        const int h = p / 96, w = p - (p / 96) * 96;
        const float fw = (float)w, fh = (float)h;
        // geo taps
        float ix = fmaf(g0, fw, fmaf(g1, fh, gcx));
        float iy = fmaf(g3, fw, fmaf(g4, fh, gcy));
        ix = fminf(fmaxf(ix, -1.f), 96.f);
        iy = fminf(fmaxf(iy, -1.f), 96.f);
        const float x0f = floorf(ix), y0f = floorf(iy);
        const float fx = ix - x0f, fy = iy - y0f;
        const int base = ((int)y0f + 1) * HP + ((int)x0f + 1);
        const float m00 = m[base],      m01 = m[base + 1];
        const float m10 = m[base + HP], m11 = m[base + HP + 1];
        const float mx0 = fmaf(fx, m01 - m00, m00);
        const float mx1 = fmaf(fx, m11 - m10, m10);
        float v = fmaf(fy, mx1 - mx0, mx0);
        // box weight (sample of ones)
        const float bx = fmaf(b0, fw, fmaf(b1, fh, bcx));
        const float by = fmaf(b3, fw, fmaf(b4, fh, bcy));
        const float Xs = fminf(clamp01(bx + 1.f), clamp01(96.f - bx));
        const float Ys = fminf(clamp01(by + 1.f), clamp01(96.f - by));
        v *= Xs * Ys;
        if (RES) v += o[p];
        o[p] = v;
        if (POOL) psum += v;
    }
    if (POOL) {
        #pragma unroll
        for (int off = 32; off > 0; off >>= 1) psum += __shfl_down(psum, off, 64);
        __shared__ float red[6];
        if ((t & 63) == 0) red[t >> 6] = psum;
        __syncthreads();
        if (t == 0) {
            float s = 0.f;
            #pragma unroll
            for (int i = 0; i < 6; ++i) s += red[i];
            pooled[b * NCH + c] = s * (1.f / (float)NPIX);
        }
    }
}

// ---------------- mean pool (fallback when ws has no room for pooled) ----------------
__global__ __launch_bounds__(256) void pool_kernel(const float* __restrict__ feat,
                                                   float* __restrict__ pooled) {
    const int bc = blockIdx.x;           // b*128 + c
    const float4* f = (const float4*)(feat + (size_t)bc * NPIX);
    float s = 0.f;
    for (int i = threadIdx.x; i < NPIX / 4; i += 256) {
        const float4 v = f[i];
        s += (v.x + v.y) + (v.z + v.w);
    }
    #pragma unroll
    for (int off = 32; off > 0; off >>= 1) s += __shfl_down(s, off, 64);
    __shared__ float red[4];
    if ((threadIdx.x & 63) == 0) red[threadIdx.x >> 6] = s;
    __syncthreads();
    if (threadIdx.x == 0)
        pooled[bc] = (red[0] + red[1] + red[2] + red[3]) * (1.f / (float)NPIX);
}

// ---------------- dense: logits[b,n] = pooled[b,:] . W[n,:] + bias[n] ----------------
__global__ __launch_bounds__(256) void dense_kernel(const float* __restrict__ pooled,
                                                    const float* __restrict__ Wt,
                                                    const float* __restrict__ bias,
                                                    float* __restrict__ out) {
    const int idx = blockIdx.x * 256 + threadIdx.x;
    if (idx >= NB * 1000) return;
    const int b = idx / 1000, n = idx - b * 1000;
    float acc = bias[n];
    const float* p = pooled + b * NCH;
    const float* wr = Wt + n * NCH;
    #pragma unroll 4
    for (int c = 0; c < NCH; ++c) acc = fmaf(p[c], wr[c], acc);
    out[idx] = acc;
}

extern "C" void kernel_launch(void* const* d_in, const int* in_sizes, int n_in,
                              void* d_out, int out_size, void* d_ws, size_t ws_size,
                              hipStream_t stream) {
    const float* x       = (const float*)d_in[0];   // [16,64,96,96]
    const float* in_geo  = (const float*)d_in[1];   // [128,2,3]
    const float* in_box  = (const float*)d_in[2];   // [128,2,3]
    const float* in_lin  = (const float*)d_in[3];   // [128,64]
    const float* lay_geo = (const float*)d_in[4];   // [4,128,2,3]
    const float* lay_box = (const float*)d_in[5];   // [4,128,2,3]
    const float* lay_lin = (const float*)d_in[6];   // [4,128,128]
    const float* dense_w = (const float*)d_in[7];   // [1000,128]
    const float* dense_b = (const float*)d_in[8];   // [1000]

    float* out  = (float*)d_out;
    float* feat = out + NB * 1000;                  // [16,128,96,96] lives in d_out
    float* mixed = (float*)d_ws;                    // 75.5 MB scratch

    const size_t mixedFloats = (size_t)NB * NCH * NPIX;
    const bool fusedPool = ws_size >= (mixedFloats + NB * NCH) * sizeof(float);
    float* pooled = fusedPool ? (float*)d_ws + mixedFloats : (float*)d_ws;

    const dim3 mixGrid(NPIX / 256, NB);             // 36 x 16 blocks of 512
    const dim3 smpGrid(NCH, NB);

    mix_kernel<64><<<mixGrid, 512, 0, stream>>>(x, in_lin, mixed);
    sample_kernel<false, false><<<smpGrid, 384, 0, stream>>>(mixed, in_geo, in_box, feat, pooled);
    for (int i = 0; i < 3; ++i) {
        mix_kernel<128><<<mixGrid, 512, 0, stream>>>(feat, lay_lin + i * NCH * NCH, mixed);
        sample_kernel<true, false><<<smpGrid, 384, 0, stream>>>(mixed, lay_geo + i * NCH * 6,
                                                                lay_box + i * NCH * 6, feat, pooled);
    }
    mix_kernel<128><<<mixGrid, 512, 0, stream>>>(feat, lay_lin + 3 * NCH * NCH, mixed);
    if (fusedPool) {
        sample_kernel<true, true><<<smpGrid, 384, 0, stream>>>(mixed, lay_geo + 3 * NCH * 6,
                                                               lay_box + 3 * NCH * 6, feat, pooled);
    } else {
        sample_kernel<true, false><<<smpGrid, 384, 0, stream>>>(mixed, lay_geo + 3 * NCH * 6,
                                                                lay_box + 3 * NCH * 6, feat, pooled);
        pool_kernel<<<NB * NCH, 256, 0, stream>>>(feat, pooled);
    }
    dense_kernel<<<(NB * 1000 + 255) / 256, 256, 0, stream>>>(pooled, dense_w, dense_b, out);
}

// Round 6
// 569.538 us; speedup vs baseline: 2.2933x; 1.0980x over previous
//
#include <hip/hip_runtime.h>

#define HW 96
#define NPIX 9216      // 96*96
#define NCH 128
#define NB 16
#define HP 98          // haloed plane dim (coords -1..96)

// ---------------- channel mix: mixed[b,c,p] = sum_i lin[c,i] * x[b,i,p] ----------------
// No-LDS GEMM. Block = 512 thr (8 waves), tile = 128 px x 128 ch, thread = 2 px,
// wave = 16 ch (lin wave-uniform -> s_load_dwordx8 into SGPRs, the 1 allowed
// SGPR operand of v_fma). Grid 1152 blocks (4.5/CU) fixes R5's 2.25-blocks/CU
// imbalance; acc 32 + xv 16 ~ 60 VGPR -> 6-8 waves/SIMD for latency hiding.
// (R5: 4px/thread, 576 blocks -> Occ 31%, VALU 42% = pure-FMA duty, 78us.)
template<int K>
__global__ __launch_bounds__(512, 4) void mix_kernel(const float* __restrict__ x,
                                                     const float* __restrict__ lin,
                                                     float* __restrict__ mixed) {
    const int b    = blockIdx.y;
    const int lane = threadIdx.x & 63;
    const int p    = blockIdx.x * 128 + lane * 2;
    const int c0   = __builtin_amdgcn_readfirstlane((threadIdx.x >> 6) * 16);
    const float* xb = x + (size_t)b * K * NPIX + p;
    const float* lr = lin + c0 * K;

    float2 acc[16];
    #pragma unroll
    for (int c = 0; c < 16; ++c) acc[c] = float2{0.f, 0.f};

    for (int k0 = 0; k0 < K; k0 += 8) {
        float2 xv[8];
        #pragma unroll
        for (int j = 0; j < 8; ++j)
            xv[j] = *(const float2*)&xb[(size_t)(k0 + j) * NPIX];
        #pragma unroll
        for (int c = 0; c < 16; ++c) {
            const float* lc = lr + c * K + k0;     // wave-uniform -> s_load_dwordx8
            #pragma unroll
            for (int j = 0; j < 8; ++j) {
                acc[c].x = fmaf(lc[j], xv[j].x, acc[c].x);
                acc[c].y = fmaf(lc[j], xv[j].y, acc[c].y);
            }
        }
    }
    float* ob = mixed + (size_t)b * NCH * NPIX + p;
    #pragma unroll
    for (int c = 0; c < 16; ++c)
        *(float2*)&ob[(size_t)(c0 + c) * NPIX] = acc[c];
}

__device__ inline float clamp01(float z) { return fminf(fmaxf(z, 0.f), 1.f); }

// ---------------- bilinear affine sample (zero-halo LDS plane) ----------------
// Plane staged into LDS with a 1px zero border (coords -1..96). ix clamped to
// [-1,96]: every out-of-range tap then reads a zero cell with the correct
// weight, eliminating all validity masks. Box-sample-of-ones factorizes:
// bw = min(clamp01(bx+1), clamp01(96-bx)) * (same in y). 2-lerp form = 6 FMA.
template<bool RES, bool POOL>
__global__ __launch_bounds__(384) void sample_kernel(const float* __restrict__ mixed,
                                                     const float* __restrict__ geo,
                                                     const float* __restrict__ box,
                                                     float* __restrict__ out,
                                                     float* __restrict__ pooled) {
    __shared__ float m[HP * HP];           // 38.4 KB -> 4 blocks/CU, 24 waves/CU
    const int c = blockIdx.x;
    const int b = blockIdx.y;
    const int t = threadIdx.x;
    // zero only the halo border (interior is fully overwritten by the fill)
    if (t < HP) {                           // top & bottom rows
        m[t] = 0.f;
        m[(HP - 1) * HP + t] = 0.f;
    } else if (t < HP + 96) {               // left & right columns (rows 1..96)
        const int h = t - HP + 1;
        m[h * HP] = 0.f;
        m[h * HP + HP - 1] = 0.f;
    }
    const float* src = mixed + ((size_t)b * NCH + c) * NPIX;
    #pragma unroll
    for (int r = 0; r < NPIX / 384; ++r) {
        const int idx = r * 384 + t;
        const int h = idx / 96, w = idx - (idx / 96) * 96;
        m[(h + 1) * HP + (w + 1)] = src[idx];
    }
    const float* gth = geo + c * 6;
    const float* bth = box + c * 6;
    const float g0 = gth[0], g1 = gth[1], g3 = gth[3], g4 = gth[4];
    const float gcx = 48.f * gth[2] - 47.5f * (g0 + g1) + 47.5f;
    const float gcy = 48.f * gth[5] - 47.5f * (g3 + g4) + 47.5f;
    const float b0 = bth[0], b1 = bth[1], b3 = bth[3], b4 = bth[4];
    const float bcx = 48.f * bth[2] - 47.5f * (b0 + b1) + 47.5f;
    const float bcy = 48.f * bth[5] - 47.5f * (b3 + b4) + 47.5f;
    float* o = out + ((size_t)b * NCH + c) * NPIX;
    __syncthreads();
    float psum = 0.f;
    #pragma unroll 4
    for (int r = 0; r < NPIX / 384; ++r) {
        const int p = r * 384 + t;
        const int h = p / 96, w = p - (p / 96) * 96;
        const float fw = (float)w, fh = (float)h;
        float ix = fmaf(g0, fw, fmaf(g1, fh, gcx));
        float iy = fmaf(g3, fw, fmaf(g4, fh, gcy));
        ix = fminf(fmaxf(ix, -1.f), 96.f);
        iy = fminf(fmaxf(iy, -1.f), 96.f);
        const float x0f = floorf(ix), y0f = floorf(iy);
        const float fx = ix - x0f, fy = iy - y0f;
        const int base = ((int)y0f + 1) * HP + ((int)x0f + 1);
        const float m00 = m[base],      m01 = m[base + 1];
        const float m10 = m[base + HP], m11 = m[base + HP + 1];
        const float mx0 = fmaf(fx, m01 - m00, m00);
        const float mx1 = fmaf(fx, m11 - m10, m10);
        float v = fmaf(fy, mx1 - mx0, mx0);
        const float bx = fmaf(b0, fw, fmaf(b1, fh, bcx));
        const float by = fmaf(b3, fw, fmaf(b4, fh, bcy));
        const float Xs = fminf(clamp01(bx + 1.f), clamp01(96.f - bx));
        const float Ys = fminf(clamp01(by + 1.f), clamp01(96.f - by));
        v *= Xs * Ys;
        if (RES) v += o[p];
        o[p] = v;
        if (POOL) psum += v;
    }
    if (POOL) {
        #pragma unroll
        for (int off = 32; off > 0; off >>= 1) psum += __shfl_down(psum, off, 64);
        __shared__ float red[6];
        if ((t & 63) == 0) red[t >> 6] = psum;
        __syncthreads();
        if (t == 0) {
            float s = 0.f;
            #pragma unroll
            for (int i = 0; i < 6; ++i) s += red[i];
            pooled[b * NCH + c] = s * (1.f / (float)NPIX);
        }
    }
}

// ---------------- mean pool (fallback when ws has no room for pooled) ----------------
__global__ __launch_bounds__(256) void pool_kernel(const float* __restrict__ feat,
                                                   float* __restrict__ pooled) {
    const int bc = blockIdx.x;           // b*128 + c
    const float4* f = (const float4*)(feat + (size_t)bc * NPIX);
    float s = 0.f;
    for (int i = threadIdx.x; i < NPIX / 4; i += 256) {
        const float4 v = f[i];
        s += (v.x + v.y) + (v.z + v.w);
    }
    #pragma unroll
    for (int off = 32; off > 0; off >>= 1) s += __shfl_down(s, off, 64);
    __shared__ float red[4];
    if ((threadIdx.x & 63) == 0) red[threadIdx.x >> 6] = s;
    __syncthreads();
    if (threadIdx.x == 0)
        pooled[bc] = (red[0] + red[1] + red[2] + red[3]) * (1.f / (float)NPIX);
}

// ---------------- dense: logits[b,n] = pooled[b,:] . W[n,:] + bias[n] ----------------
__global__ __launch_bounds__(256) void dense_kernel(const float* __restrict__ pooled,
                                                    const float* __restrict__ Wt,
                                                    const float* __restrict__ bias,
                                                    float* __restrict__ out) {
    const int idx = blockIdx.x * 256 + threadIdx.x;
    if (idx >= NB * 1000) return;
    const int b = idx / 1000, n = idx - b * 1000;
    float acc = bias[n];
    const float* p = pooled + b * NCH;
    const float* wr = Wt + n * NCH;
    #pragma unroll 4
    for (int c = 0; c < NCH; ++c) acc = fmaf(p[c], wr[c], acc);
    out[idx] = acc;
}

extern "C" void kernel_launch(void* const* d_in, const int* in_sizes, int n_in,
                              void* d_out, int out_size, void* d_ws, size_t ws_size,
                              hipStream_t stream) {
    const float* x       = (const float*)d_in[0];   // [16,64,96,96]
    const float* in_geo  = (const float*)d_in[1];   // [128,2,3]
    const float* in_box  = (const float*)d_in[2];   // [128,2,3]
    const float* in_lin  = (const float*)d_in[3];   // [128,64]
    const float* lay_geo = (const float*)d_in[4];   // [4,128,2,3]
    const float* lay_box = (const float*)d_in[5];   // [4,128,2,3]
    const float* lay_lin = (const float*)d_in[6];   // [4,128,128]
    const float* dense_w = (const float*)d_in[7];   // [1000,128]
    const float* dense_b = (const float*)d_in[8];   // [1000]

    float* out  = (float*)d_out;
    float* feat = out + NB * 1000;                  // [16,128,96,96] lives in d_out
    float* mixed = (float*)d_ws;                    // 75.5 MB scratch

    const size_t mixedFloats = (size_t)NB * NCH * NPIX;
    const bool fusedPool = ws_size >= (mixedFloats + NB * NCH) * sizeof(float);
    float* pooled = fusedPool ? (float*)d_ws + mixedFloats : (float*)d_ws;

    const dim3 mixGrid(NPIX / 128, NB);             // 72 x 16 = 1152 blocks of 512
    const dim3 smpGrid(NCH, NB);

    mix_kernel<64><<<mixGrid, 512, 0, stream>>>(x, in_lin, mixed);
    sample_kernel<false, false><<<smpGrid, 384, 0, stream>>>(mixed, in_geo, in_box, feat, pooled);
    for (int i = 0; i < 3; ++i) {
        mix_kernel<128><<<mixGrid, 512, 0, stream>>>(feat, lay_lin + i * NCH * NCH, mixed);
        sample_kernel<true, false><<<smpGrid, 384, 0, stream>>>(mixed, lay_geo + i * NCH * 6,
                                                                lay_box + i * NCH * 6, feat, pooled);
    }
    mix_kernel<128><<<mixGrid, 512, 0, stream>>>(feat, lay_lin + 3 * NCH * NCH, mixed);
    if (fusedPool) {
        sample_kernel<true, true><<<smpGrid, 384, 0, stream>>>(mixed, lay_geo + 3 * NCH * 6,
                                                               lay_box + 3 * NCH * 6, feat, pooled);
    } else {
        sample_kernel<true, false><<<smpGrid, 384, 0, stream>>>(mixed, lay_geo + 3 * NCH * 6,
                                                                lay_box + 3 * NCH * 6, feat, pooled);
        pool_kernel<<<NB * NCH, 256, 0, stream>>>(feat, pooled);
    }
    dense_kernel<<<(NB * 1000 + 255) / 256, 256, 0, stream>>>(pooled, dense_w, dense_b, out);
}